// Round 2
// baseline (172.152 us; speedup 1.0000x reference)
//
#include <hip/hip_runtime.h>

#define BB 2
#define NN 16384
#define CC 64
#define SS 4096
#define KK 32
#define R2 0.16f   // RADIUS^2

// spatial grid: cell = RADIUS, 24^3 cells covering [-4.8, 4.8] (clamped; the
// clamp is monotone so the 3x3x3 neighborhood remains a superset of the ball
// for ANY input magnitude — tail points just pile into edge cells)
#define GD   24
#define GC   (GD * GD * GD)       // 13824 cells per batch
#define GCP  (GC + 4)             // offs stride (GC+1 used)
#define CAP  512                  // per-wave hit-list capacity (max expected ~360)
#define CAPL (CAP / 64)           // 8 register chunks for selection

typedef __bf16 bf16x8 __attribute__((ext_vector_type(8)));
typedef float  f32x4  __attribute__((ext_vector_type(4)));

#define MFMA(a, b, c) __builtin_amdgcn_mfma_f32_16x16x32_bf16((a), (b), (c), 0, 0, 0)

static __device__ __forceinline__ ushort f2bf(float f) {
    __bf16 h = (__bf16)f;
    return *(ushort*)&h;
}

static __device__ __forceinline__ int cellc(float x) {
    int i = (int)floorf(x * 2.5f + 12.0f);
    return i < 0 ? 0 : (i > GD - 1 ? GD - 1 : i);
}

// workspace section offsets (bytes), all 16B aligned
#define WS_PTS4   0          // pts4:    2*16384*16    =   524,288
#define WS_FEAT   524288     // feat_nc: 2*16384*64*2  = 4,194,304
#define WS_W1T    4718592    // 64*96*2   = 12,288
#define WS_W2T    4730880    // 64*64*2   =  8,192
#define WS_W3T    4739072    // 128*64*2  = 16,384
#define WS_SPTS   4755456    // sorted pts float4: 524,288
#define WS_SSID   5279744    // sorted orig idx:   131,072
#define WS_CELLS  5410816    // per-point cell id ushort: 2*16384*2 = 65,536
#define WS_OFF    5476352    // offsets: 2*13828*4 = 110,624  (end 5,586,976)

// prep index ranges
#define T_PTS   (BB * NN)                  // 32768
#define T_W1    (T_PTS + 64 * 96)          // 38912
#define T_W2    (T_W1 + 64 * 64)           // 43008
#define T_W3    (T_W2 + 128 * 64)          // 51200
#define T_NXYZ  (T_W3 + BB * SS * 3)       // 75776
#define T_SIDX  (T_NXYZ + BB * SS)         // 83968
#define T_ALL   (T_SIDX + BB * NN * 8)     // 346112 (feat threads, 8x split)

// ---------------------------------------------------------------------------
// prep: pts4=(x,y,z,|x|^2) + per-point cell id; bf16 weight transposes;
// coalesced new_xyz copy; samp_idx; feat [B][C][N] fp32 -> [B][N][C] bf16
// (8 threads/point). No atomics. One launch.
// ---------------------------------------------------------------------------
__global__ __launch_bounds__(256) void prep_kernel(
        const float* __restrict__ xyz, const float* __restrict__ feat,
        const float* __restrict__ W1, const float* __restrict__ W2,
        const float* __restrict__ W3,
        float4* __restrict__ pts4, ushort* __restrict__ feat_nc,
        ushort* __restrict__ W1t, ushort* __restrict__ W2t,
        ushort* __restrict__ W3t,
        float* __restrict__ out_xyz, float* __restrict__ out_sidx,
        ushort* __restrict__ cells) {
    const int t = blockIdx.x * 256 + threadIdx.x;
    if (t < T_PTS) {
        const float* p = xyz + (size_t)t * 3;
        const float x = p[0], y = p[1], z = p[2];
        pts4[t] = make_float4(x, y, z, x * x + y * y + z * z);
        cells[t] = (ushort)((cellc(z) * GD + cellc(y)) * GD + cellc(x));
    } else if (t < T_W1) {
        const int i = t - T_PTS;
        const int n = i / 96, k = i - n * 96;
        float v = 0.0f;
        if (k < 64) v = W1[(3 + k) * 64 + n];
        else if (k < 67) v = W1[(k - 64) * 64 + n];
        W1t[n * 96 + k] = f2bf(v);
    } else if (t < T_W2) {
        const int i = t - T_W1;
        const int n = i >> 6, k = i & 63;
        W2t[n * 64 + k] = f2bf(W2[k * 64 + n]);
    } else if (t < T_W3) {
        const int i = t - T_W2;
        const int n = i >> 6, k = i & 63;
        W3t[n * 64 + k] = f2bf(W3[k * 128 + n]);
    } else if (t < T_NXYZ) {
        const int i = t - T_W3;              // new_xyz = xyz[:, :SS] copy
        const int b = i / (SS * 3), j = i - b * (SS * 3);
        out_xyz[i] = xyz[(size_t)b * NN * 3 + j];
    } else if (t < T_SIDX) {
        const int i = t - T_NXYZ;
        out_sidx[i] = (float)(i & (SS - 1));
    } else if (t < T_ALL) {
        const int j = t - T_SIDX;            // 0 .. BB*NN*8-1
        const int nl = j >> 3, c8 = j & 7;   // nl: linear point, c8: channel oct
        const int b = nl >> 14, n = nl & (NN - 1);
        const float* fb = feat + (size_t)b * CC * NN + n;
        uint u[4];
        #pragma unroll
        for (int q = 0; q < 4; ++q) {
            const float f0 = fb[(size_t)(c8 * 8 + 2 * q) * NN];
            const float f1 = fb[(size_t)(c8 * 8 + 2 * q + 1) * NN];
            u[q] = (uint)f2bf(f0) | ((uint)f2bf(f1) << 16);
        }
        *(uint4*)(feat_nc + (size_t)nl * 64 + c8 * 8) = make_uint4(u[0], u[1], u[2], u[3]);
    }
}

// ---------------------------------------------------------------------------
// bin: one block per batch. LDS histogram (13824 cells, 55KB) -> in-block
// scan -> offsets to global -> LDS-cursor counting-sort scatter. Replaces
// the old memset + scan + scatter dispatches (and their serial latencies).
// ---------------------------------------------------------------------------
#define CH 14                               // cells per thread (1024*14 >= GC)
__global__ __launch_bounds__(1024) void bin_kernel(
        const float4* __restrict__ pts4, const ushort* __restrict__ cells,
        float4* __restrict__ spts, int* __restrict__ ssid,
        uint* __restrict__ offs) {
    __shared__ uint hist[GC];
    __shared__ uint wsum[17];
    const int b = blockIdx.x, t = threadIdx.x;
    const ushort* cb = cells + (size_t)b * NN;

    for (int i = t; i < GC; i += 1024) hist[i] = 0u;
    __syncthreads();
    for (int i = t; i < NN; i += 1024) atomicAdd(&hist[cb[i]], 1u);
    __syncthreads();

    // per-thread serial sums over a contiguous CH-cell chunk
    uint c[CH];
    uint s = 0;
    #pragma unroll
    for (int j = 0; j < CH; ++j) {
        const int ci = t * CH + j;
        c[j] = (ci < GC) ? hist[ci] : 0u;
        s += c[j];
    }
    // wave inclusive scan of s, then cross-wave exclusive via tiny LDS
    const int lane = t & 63, wid = t >> 6;
    uint inc = s;
    #pragma unroll
    for (int o = 1; o < 64; o <<= 1) {
        const uint u = __shfl_up(inc, o);
        inc += (lane >= o) ? u : 0u;
    }
    if (lane == 63) wsum[wid] = inc;
    __syncthreads();
    if (t == 0) {
        uint r = 0;
        #pragma unroll
        for (int k = 0; k < 16; ++k) { const uint v2 = wsum[k]; wsum[k] = r; r += v2; }
    }
    __syncthreads();
    uint run = wsum[wid] + inc - s;          // exclusive prefix for this thread
    uint* offb = offs + (size_t)b * GCP;
    #pragma unroll
    for (int j = 0; j < CH; ++j) {
        const int ci = t * CH + j;
        if (ci < GC) { offb[ci] = run; hist[ci] = run; run += c[j]; }
    }
    if (t == 1023) offb[GC] = NN;
    __syncthreads();

    // scatter (order within cell nondeterministic — harmless: the fused
    // kernel selects by smallest original index, a set-invariant)
    for (int i = t; i < NN; i += 1024) {
        const int cell = cb[i];
        const uint pos = atomicAdd(&hist[cell], 1u);
        spts[(size_t)b * NN + pos] = pts4[(size_t)b * NN + i];
        ssid[(size_t)b * NN + pos] = i;
    }
}

// ---------------------------------------------------------------------------
// fused: one wave = one centroid. Grid ball-query with a FLATTENED candidate
// loop: all 18 run offsets loaded up front (one latency), 9-entry prefix
// table in registers (constant-indexed), one dense coalesced loop over the
// candidate union. Selection of the 32 smallest ids via binary search with
// ballot-popcount counting (no shuffle-reduce chains). Then gather + 3-layer
// MLP + maxpool, unchanged.
// ---------------------------------------------------------------------------
__global__ __launch_bounds__(256, 2) void fused_kernel(
        const float4* __restrict__ pts4, const ushort* __restrict__ feat_nc,
        const float4* __restrict__ spts, const int* __restrict__ ssid,
        const uint* __restrict__ offs,
        const ushort* __restrict__ W1t, const ushort* __restrict__ W2t,
        const ushort* __restrict__ W3t,
        const float* __restrict__ b1, const float* __restrict__ b2,
        const float* __restrict__ b3, float* __restrict__ out_feat) {
    const int w = threadIdx.x >> 6, lane = threadIdx.x & 63;
    const int quad = lane >> 4, mrow = lane & 15;
    const int m = lane & 31, half = lane >> 5;

    __shared__ __align__(16) ushort ldsA[4][32 * 104];   // hits -> g -> h1 -> h2
    __shared__ float stage[128][5];                      // [ch][4 s + pad]
    ushort* gbuf = ldsA[w];
    int* hit = (int*)gbuf;                               // 2KB bq scratch (CAP ints)

    const int xcd = blockIdx.x & 7;
    const int slot = blockIdx.x >> 3;              // 0..255
    const int b = xcd >> 2;
    const int s0 = ((xcd & 3) * 256 + slot) * 4;   // block's 4-s tile
    const int s = s0 + w;

    const float4* pb = pts4 + (size_t)b * NN;
    const ushort* fbase = feat_nc + (size_t)b * NN * 64;
    const unsigned long long ltmask = (1ull << lane) - 1ull;

    // ================= ball query via grid (flattened) =================
    {
        const float4 c = pb[s];
        const int cx = cellc(c.x), cy = cellc(c.y), cz = cellc(c.z);
        const int x0 = cx - 1 < 0 ? 0 : cx - 1;
        const int x1 = cx + 1 > GD - 1 ? GD - 1 : cx + 1;
        const uint* off = offs + (size_t)b * GCP;
        const float4* sp = spts + (size_t)b * NN;
        const int* sidp = ssid + (size_t)b * NN;

        int rs[9], re[9], pre[10];
        pre[0] = 0;
        #pragma unroll
        for (int e = 0; e < 9; ++e) {
            const int z = cz + e / 3 - 1, y = cy + e % 3 - 1;
            const bool ok = (z >= 0) && (z < GD) && (y >= 0) && (y < GD);
            const int cbase = (z * GD + y) * GD;
            const int a = ok ? (int)off[cbase + x0] : 0;
            const int bnd = ok ? (int)off[cbase + x1 + 1] : 0;
            rs[e] = a;
            re[e] = ok ? bnd : a;
            pre[e + 1] = pre[e] + (re[e] - rs[e]);
        }
        const int tot = pre[9];

        int cnt = 0;
        for (int g0 = 0; g0 < tot; g0 += 64) {
            const int g = g0 + lane;
            int adj = rs[0];                       // pre[0] == 0
            #pragma unroll
            for (int k = 1; k < 9; ++k) adj = (g >= pre[k]) ? (rs[k] - pre[k]) : adj;
            const bool act = g < tot;
            const int idx = act ? (g + adj) : 0;
            const float4 p = sp[idx];
            const int id = sidp[idx];
            const float d = c.w + p.w - 2.0f * (c.x * p.x + c.y * p.y + c.z * p.z);
            const bool h = act && (d < R2);
            const unsigned long long mk = __ballot(h);
            if (h) {
                const int pp = cnt + __popcll(mk & ltmask);
                if (pp < CAP) hit[pp] = id;
            }
            cnt += (int)__popcll(mk);
        }

        // ---- keep the 32 smallest original indices (set-equivalent to the
        // reference "first nsample in index order"; maxpool ignores order) ----
        if (cnt > KK) {
            const int stored = cnt < CAP ? cnt : CAP;
            int v[CAPL];
            #pragma unroll
            for (int j = 0; j < CAPL; ++j) {
                const int q = j * 64 + lane;
                const int val = hit[q];            // within allocated LDS
                v[j] = (q < stored) ? val : 0x7fffffff;
            }
            int lo = 0, hi = NN - 1;
            while (lo < hi) {                      // wave-uniform, <=14 iters
                const int mid = (lo + hi) >> 1;
                int cle = 0;
                #pragma unroll
                for (int j = 0; j < CAPL; ++j)
                    if (j * 64 < stored)           // wave-uniform chunk gate
                        cle += (int)__popcll(__ballot(v[j] <= mid));
                if (cle >= KK) hi = mid; else lo = mid + 1;
            }
            int pos = 0;                           // exactly KK selected (ids unique)
            #pragma unroll
            for (int j = 0; j < CAPL; ++j) {
                if (j * 64 < stored) {
                    const bool sel = v[j] <= lo;
                    const unsigned long long mk = __ballot(sel);
                    if (sel) hit[pos + __popcll(mk & ltmask)] = v[j];
                    pos += (int)__popcll(mk);
                }
            }
        } else if (lane < KK) {
            const int vv = (cnt == 0) ? 0 : ((lane < cnt) ? hit[lane] : hit[0]);
            hit[lane] = vv;
        }
    }

    // ================= gather: sid (LDS) -> rows -> LDS =================
    {
        const int sid = hit[m];                  // wave-private, program order
        const ushort* src = fbase + (size_t)sid * 64 + half * 32;
        ushort* dst = gbuf + m * 104 + half * 32;
        uint4 rows[4];
        #pragma unroll
        for (int i = 0; i < 4; ++i) rows[i] = *(const uint4*)(src + i * 8);
        const float4 p = pb[sid];
        const float4 cc = pb[s];
        #pragma unroll
        for (int i = 0; i < 4; ++i) *(uint4*)(dst + i * 8) = rows[i];
        if (half == 0) {
            bf16x8 rel = {(__bf16)(p.x - cc.x), (__bf16)(p.y - cc.y),
                          (__bf16)(p.z - cc.z), (__bf16)0.f,
                          (__bf16)0.f, (__bf16)0.f, (__bf16)0.f, (__bf16)0.f};
            *(bf16x8*)(gbuf + m * 104 + 64) = rel;
            *(uint4*)(gbuf + m * 104 + 88) = make_uint4(0, 0, 0, 0);
        } else {
            *(uint4*)(gbuf + m * 104 + 72) = make_uint4(0, 0, 0, 0);
            *(uint4*)(gbuf + m * 104 + 80) = make_uint4(0, 0, 0, 0);
        }
    }

    // ================= layer 1: [32x96]x[96x64] =================
    {
        f32x4 acc[2][4];
        #pragma unroll
        for (int nt = 0; nt < 4; ++nt) {
            const float bv = b1[nt * 16 + mrow];
            acc[0][nt] = (f32x4){bv, bv, bv, bv};
            acc[1][nt] = acc[0][nt];
        }
        #pragma unroll
        for (int ks = 0; ks < 3; ++ks) {
            const bf16x8 a0 = *(const bf16x8*)(gbuf + mrow * 104 + ks * 32 + quad * 8);
            const bf16x8 a1 = *(const bf16x8*)(gbuf + (16 + mrow) * 104 + ks * 32 + quad * 8);
            #pragma unroll
            for (int nt = 0; nt < 4; ++nt) {
                const bf16x8 wf = *(const bf16x8*)(W1t + (nt * 16 + mrow) * 96 + ks * 32 + quad * 8);
                acc[0][nt] = MFMA(a0, wf, acc[0][nt]);
                acc[1][nt] = MFMA(a1, wf, acc[1][nt]);
            }
        }
        #pragma unroll
        for (int mt = 0; mt < 2; ++mt)
            #pragma unroll
            for (int nt = 0; nt < 4; ++nt)
                #pragma unroll
                for (int r = 0; r < 4; ++r)
                    gbuf[(mt * 16 + quad * 4 + r) * 104 + nt * 16 + mrow] =
                        f2bf(fmaxf(acc[mt][nt][r], 0.0f));
    }

    // ================= layer 2: [32x64]x[64x64] =================
    {
        f32x4 acc[2][4];
        #pragma unroll
        for (int nt = 0; nt < 4; ++nt) {
            const float bv = b2[nt * 16 + mrow];
            acc[0][nt] = (f32x4){bv, bv, bv, bv};
            acc[1][nt] = acc[0][nt];
        }
        #pragma unroll
        for (int ks = 0; ks < 2; ++ks) {
            const bf16x8 a0 = *(const bf16x8*)(gbuf + mrow * 104 + ks * 32 + quad * 8);
            const bf16x8 a1 = *(const bf16x8*)(gbuf + (16 + mrow) * 104 + ks * 32 + quad * 8);
            #pragma unroll
            for (int nt = 0; nt < 4; ++nt) {
                const bf16x8 wf = *(const bf16x8*)(W2t + (nt * 16 + mrow) * 64 + ks * 32 + quad * 8);
                acc[0][nt] = MFMA(a0, wf, acc[0][nt]);
                acc[1][nt] = MFMA(a1, wf, acc[1][nt]);
            }
        }
        #pragma unroll
        for (int mt = 0; mt < 2; ++mt)
            #pragma unroll
            for (int nt = 0; nt < 4; ++nt)
                #pragma unroll
                for (int r = 0; r < 4; ++r)
                    gbuf[(mt * 16 + quad * 4 + r) * 104 + nt * 16 + mrow] =
                        f2bf(fmaxf(acc[mt][nt][r], 0.0f));
    }

    // ============ layer 3: [32x64]x[64x128] two n-halves + maxpool ==========
    #pragma unroll
    for (int nh = 0; nh < 2; ++nh) {
        f32x4 acc[2][4];
        #pragma unroll
        for (int ntl = 0; ntl < 4; ++ntl) {
            const float bv = b3[(nh * 4 + ntl) * 16 + mrow];
            acc[0][ntl] = (f32x4){bv, bv, bv, bv};
            acc[1][ntl] = acc[0][ntl];
        }
        #pragma unroll
        for (int ks = 0; ks < 2; ++ks) {
            const bf16x8 a0 = *(const bf16x8*)(gbuf + mrow * 104 + ks * 32 + quad * 8);
            const bf16x8 a1 = *(const bf16x8*)(gbuf + (16 + mrow) * 104 + ks * 32 + quad * 8);
            #pragma unroll
            for (int ntl = 0; ntl < 4; ++ntl) {
                const bf16x8 wf = *(const bf16x8*)(
                    W3t + ((nh * 4 + ntl) * 16 + mrow) * 64 + ks * 32 + quad * 8);
                acc[0][ntl] = MFMA(a0, wf, acc[0][ntl]);
                acc[1][ntl] = MFMA(a1, wf, acc[1][ntl]);
            }
        }
        #pragma unroll
        for (int ntl = 0; ntl < 4; ++ntl) {
            const f32x4 v0 = acc[0][ntl], v1 = acc[1][ntl];
            float mx = fmaxf(fmaxf(v0[0], v0[1]), fmaxf(v0[2], v0[3]));
            mx = fmaxf(mx, fmaxf(fmaxf(v1[0], v1[1]), fmaxf(v1[2], v1[3])));
            mx = fmaxf(mx, __shfl_xor(mx, 16));
            mx = fmaxf(mx, __shfl_xor(mx, 32));
            mx = fmaxf(mx, 0.0f);
            if (quad == 0) stage[(nh * 4 + ntl) * 16 + mrow][w] = mx;
        }
    }
    __syncthreads();

    // ---- epilogue: 128 ch x 4 s, float2 per thread -------------------------
    {
        const int ch = threadIdx.x & 127;
        const int hf = threadIdx.x >> 7;           // 0/1
        float* dst = out_feat + ((size_t)b * 128 + ch) * SS + s0 + hf * 2;
        *(float2*)dst = make_float2(stage[ch][hf * 2], stage[ch][hf * 2 + 1]);
    }
}

// ---------------------------------------------------------------------------
extern "C" void kernel_launch(void* const* d_in, const int* in_sizes, int n_in,
                              void* d_out, int out_size, void* d_ws, size_t ws_size,
                              hipStream_t stream) {
    const float* xyz  = (const float*)d_in[0];
    const float* feat = (const float*)d_in[1];
    const float* W1   = (const float*)d_in[2];
    const float* b1   = (const float*)d_in[3];
    const float* W2   = (const float*)d_in[4];
    const float* b2   = (const float*)d_in[5];
    const float* W3   = (const float*)d_in[6];
    const float* b3   = (const float*)d_in[7];

    float* out      = (float*)d_out;
    float* out_xyz  = out;                               // [2,4096,3]
    float* out_feat = out + (size_t)BB * SS * 3;         // [2,128,4096]
    float* out_sidx = out_feat + (size_t)BB * 128 * SS;  // [2,4096]

    char* ws = (char*)d_ws;
    float4* pts4    = (float4*)(ws + WS_PTS4);
    ushort* feat_nc = (ushort*)(ws + WS_FEAT);
    ushort* W1t     = (ushort*)(ws + WS_W1T);
    ushort* W2t     = (ushort*)(ws + WS_W2T);
    ushort* W3t     = (ushort*)(ws + WS_W3T);
    float4* spts    = (float4*)(ws + WS_SPTS);
    int*    ssid    = (int*)(ws + WS_SSID);
    ushort* cells   = (ushort*)(ws + WS_CELLS);
    uint*   offs    = (uint*)(ws + WS_OFF);

    prep_kernel<<<(T_ALL + 255) / 256, 256, 0, stream>>>(
        xyz, feat, W1, W2, W3, pts4, feat_nc, W1t, W2t, W3t, out_xyz, out_sidx,
        cells);
    bin_kernel<<<BB, 1024, 0, stream>>>(pts4, cells, spts, ssid, offs);
    fused_kernel<<<BB * SS / 4, 256, 0, stream>>>(pts4, feat_nc, spts, ssid, offs,
                                                  W1t, W2t, W3t, b1, b2, b3,
                                                  out_feat);
}